// Round 2
// baseline (643.255 us; speedup 1.0000x reference)
//
#include <hip/hip_runtime.h>
#include <hip/hip_cooperative_groups.h>
#include <cmath>

namespace cg = cooperative_groups;

// NTM memory op, fused single cooperative kernel with two grid syncs.
// P1: p = exp(beta*cosine(memory+eps, k+eps)) per row, per-chunk partial sums.
// P2: softmax-normalize + interpolate + circular 3-tap shift + pow(gamma),
//     per-segment pow partial sums; pv staged in w_out region.
// P3: w = pv*invn (finalized in LDS), new_memory = memory*(1 - w e^T) + w a^T
//     (nontemporal stores), r = w^T memory via block partials + 8-way atomics.
//
// Scratch plan: p staged in the not-yet-written newmem region (written P1,
// read P2, overwritten P3 -- phases separated by grid.sync). pv staged in
// w_out, read-then-overwritten by the SAME owning block in P3. Cross-phase
// reduction partials live in __device__ globals (every element written before
// read each launch; no zeroing protocol, no cross-iteration state).

namespace {
constexpr int B = 128;
constexpr int N = 8192;
constexpr int M = 64;
constexpr float F_EPS = 1e-16f;
constexpr float F_COS_EPS = 1e-8f;

constexpr int ROWS = 128;                 // rows per P1 chunk
constexpr int NCHUNK = B * (N / ROWS);    // 8192 P1 units
constexpr int SEGROWS = 1024;             // rows per P2/P3 segment
constexpr int SEG_PER_B = N / SEGROWS;    // 8
constexpr int NSEG = B * SEG_PER_B;       // 1024 segments
}

typedef float vfloat4 __attribute__((ext_vector_type(4)));

__device__ float g_part_s[NCHUNK];   // per-chunk softmax partial sums
__device__ float g_part_t[NSEG];     // per-segment pow partial sums

__global__ __launch_bounds__(256, 4) void fused_kernel(
    const float* __restrict__ memory, const float* __restrict__ k,
    const float* __restrict__ beta, const float* __restrict__ g,
    const float* __restrict__ s, const float* __restrict__ gamma,
    const float* __restrict__ w_prev, const float* __restrict__ e,
    const float* __restrict__ a, float* __restrict__ w_out,
    float* __restrict__ r_out, float* __restrict__ newmem)
{
    const int tid  = threadIdx.x;
    const int wave = tid >> 6;
    const int lane = tid & 63;
    const int grp  = lane >> 3;       // row within 8-row pack
    const int sub  = lane & 7;        // float4 slot (0..7), +8 for hi half
    const int G    = gridDim.x;

    float* const p = newmem;          // exp-score staging (dead after P2)

    __shared__ float lds_red[16];
    __shared__ float lds_wg[SEGROWS + 2];
    __shared__ float lds_w[SEGROWS];
    __shared__ float lds_sred[4][M];
    __shared__ float lds_bcast[2];

    // ------------------------- Phase 1: scores -------------------------
    for (int u = blockIdx.x; u < NCHUNK; u += G) {
        const int b     = u >> 6;
        const int chunk = u & 63;

        // zero the r accumulator (first 32 units cover B*M floats)
        if (u < (B * M) / 256) r_out[u * 256 + tid] = 0.0f;

        const float4* k4 = reinterpret_cast<const float4*>(k + (size_t)b * M);
        const float4 kva = k4[sub];
        const float4 kvb = k4[sub + 8];
        const float4 kea = make_float4(kva.x + F_EPS, kva.y + F_EPS,
                                       kva.z + F_EPS, kva.w + F_EPS);
        const float4 keb = make_float4(kvb.x + F_EPS, kvb.y + F_EPS,
                                       kvb.z + F_EPS, kvb.w + F_EPS);
        float kn2 = kea.x*kea.x + kea.y*kea.y + kea.z*kea.z + kea.w*kea.w
                  + keb.x*keb.x + keb.y*keb.y + keb.z*keb.z + keb.w*keb.w;
        #pragma unroll
        for (int m = 1; m <= 4; m <<= 1) kn2 += __shfl_xor(kn2, m, 64);
        const float knorm = sqrtf(kn2);
        const float bb = beta[b];

        const int row0 = chunk * ROWS + wave * 32;
        float psum = 0.0f;

        #pragma unroll
        for (int it = 0; it < 4; ++it) {
            const int row = row0 + it * 8 + grp;
            const float4* m4p = reinterpret_cast<const float4*>(
                memory + ((size_t)b * N + row) * M);
            const float4 mva = m4p[sub];
            const float4 mvb = m4p[sub + 8];
            const float4 mea = make_float4(mva.x + F_EPS, mva.y + F_EPS,
                                           mva.z + F_EPS, mva.w + F_EPS);
            const float4 meb = make_float4(mvb.x + F_EPS, mvb.y + F_EPS,
                                           mvb.z + F_EPS, mvb.w + F_EPS);
            float dot = mea.x*kea.x + mea.y*kea.y + mea.z*kea.z + mea.w*kea.w
                      + meb.x*keb.x + meb.y*keb.y + meb.z*keb.z + meb.w*keb.w;
            float n2  = mea.x*mea.x + mea.y*mea.y + mea.z*mea.z + mea.w*mea.w
                      + meb.x*meb.x + meb.y*meb.y + meb.z*meb.z + meb.w*meb.w;
            #pragma unroll
            for (int m = 1; m <= 4; m <<= 1) {
                dot += __shfl_xor(dot, m, 64);
                n2  += __shfl_xor(n2,  m, 64);
            }
            if (sub == 0) {
                const float denom = fmaxf(sqrtf(n2) * knorm, F_COS_EPS);
                const float pe = expf(bb * (dot / denom));
                p[(size_t)b * N + row] = pe;
                psum += pe;
            }
        }

        psum += __shfl_xor(psum, 8, 64);
        psum += __shfl_xor(psum, 16, 64);
        psum += __shfl_xor(psum, 32, 64);
        if (lane == 0) lds_red[wave] = psum;
        __syncthreads();
        if (tid == 0)
            g_part_s[u] = lds_red[0] + lds_red[1] + lds_red[2] + lds_red[3];
        __syncthreads();
    }

    cg::this_grid().sync();

    // ------------------------- Phase 2: weights ------------------------
    for (int u = blockIdx.x; u < NSEG; u += G) {
        const int b  = u >> 3;
        const int n0 = (u & 7) * SEGROWS;

        if (tid < 64) {
            float v = g_part_s[b * 64 + tid];
            #pragma unroll
            for (int m = 1; m <= 32; m <<= 1) v += __shfl_xor(v, m, 64);
            if (tid == 0) lds_bcast[0] = v;
        }
        __syncthreads();
        const float invS = 1.0f / lds_bcast[0];
        const float gb  = g[b];
        const float gS  = gb * invS;
        const float gmb = 1.0f - gb;

        #pragma unroll
        for (int j = 0; j < 4; j++) {
            const int loc = tid + j * 256;
            const int idx = b * N + n0 + loc;
            lds_wg[loc + 1] = gS * p[idx] + gmb * w_prev[idx];
        }
        if (tid == 0) {
            const int prev = (n0 - 1) & (N - 1);
            const int next = (n0 + SEGROWS) & (N - 1);
            lds_wg[0] = gS * p[b * N + prev] + gmb * w_prev[b * N + prev];
            lds_wg[SEGROWS + 1] =
                gS * p[b * N + next] + gmb * w_prev[b * N + next];
        }
        __syncthreads();

        const float s0 = s[b*3+0], s1 = s[b*3+1], s2 = s[b*3+2];
        const float gm = gamma[b];
        float lsum = 0.0f;
        #pragma unroll
        for (int j = 0; j < 4; j++) {
            const int loc = tid + j * 256;
            const float sh = lds_wg[loc] * s0 + lds_wg[loc + 1] * s1
                           + lds_wg[loc + 2] * s2;
            const float pv = powf(sh, gm);
            w_out[b * N + n0 + loc] = pv;     // stage pv (finalized in P3)
            lsum += pv;
        }
        #pragma unroll
        for (int m = 1; m <= 32; m <<= 1) lsum += __shfl_xor(lsum, m, 64);
        if (lane == 0) lds_red[wave] = lsum;
        __syncthreads();
        if (tid == 0)
            g_part_t[u] = lds_red[0] + lds_red[1] + lds_red[2] + lds_red[3];
        __syncthreads();
    }

    cg::this_grid().sync();

    // ---------------- Phase 3: finalize w + read + update ----------------
    for (int u = blockIdx.x; u < NSEG; u += G) {
        const int b  = u >> 3;
        const int n0 = (u & 7) * SEGROWS;

        if (tid == 0) {
            float t = 0.0f;
            #pragma unroll
            for (int i = 0; i < SEG_PER_B; i++) t += g_part_t[b * SEG_PER_B + i];
            lds_bcast[1] = 1.0f / (t + F_EPS);
        }
        __syncthreads();
        const float invn = lds_bcast[1];

        #pragma unroll
        for (int j = 0; j < 4; j++) {
            const int loc = tid + j * 256;
            const float w = w_out[b * N + n0 + loc] * invn;
            w_out[b * N + n0 + loc] = w;
            lds_w[loc] = w;
        }
        __syncthreads();

        const float4* e4 = reinterpret_cast<const float4*>(e + (size_t)b * M);
        const float4* a4 = reinterpret_cast<const float4*>(a + (size_t)b * M);
        const float4 eva = e4[sub], evb = e4[sub + 8];
        const float4 ava = a4[sub], avb = a4[sub + 8];

        float4 accA = make_float4(0.f, 0.f, 0.f, 0.f);
        float4 accB = make_float4(0.f, 0.f, 0.f, 0.f);
        const int rbase = n0 + wave * 256;

        #pragma unroll 4
        for (int it = 0; it < 32; ++it) {
            const int row = rbase + it * 8 + grp;
            const size_t off = ((size_t)b * N + row) * M;
            const float4* m4p = reinterpret_cast<const float4*>(memory + off);
            const float4 mva = m4p[sub];
            const float4 mvb = m4p[sub + 8];
            const float ww = lds_w[row - n0];

            vfloat4 nva, nvb;
            nva.x = mva.x * (1.0f - ww * eva.x) + ww * ava.x;
            nva.y = mva.y * (1.0f - ww * eva.y) + ww * ava.y;
            nva.z = mva.z * (1.0f - ww * eva.z) + ww * ava.z;
            nva.w = mva.w * (1.0f - ww * eva.w) + ww * ava.w;
            nvb.x = mvb.x * (1.0f - ww * evb.x) + ww * avb.x;
            nvb.y = mvb.y * (1.0f - ww * evb.y) + ww * avb.y;
            nvb.z = mvb.z * (1.0f - ww * evb.z) + ww * avb.z;
            nvb.w = mvb.w * (1.0f - ww * evb.w) + ww * avb.w;
            __builtin_nontemporal_store(nva, (vfloat4*)(newmem + off) + sub);
            __builtin_nontemporal_store(nvb, (vfloat4*)(newmem + off) + sub + 8);

            accA.x += ww * mva.x;  accA.y += ww * mva.y;
            accA.z += ww * mva.z;  accA.w += ww * mva.w;
            accB.x += ww * mvb.x;  accB.y += ww * mvb.y;
            accB.z += ww * mvb.z;  accB.w += ww * mvb.w;
        }

        #pragma unroll
        for (int m = 8; m <= 32; m <<= 1) {
            accA.x += __shfl_xor(accA.x, m, 64);
            accA.y += __shfl_xor(accA.y, m, 64);
            accA.z += __shfl_xor(accA.z, m, 64);
            accA.w += __shfl_xor(accA.w, m, 64);
            accB.x += __shfl_xor(accB.x, m, 64);
            accB.y += __shfl_xor(accB.y, m, 64);
            accB.z += __shfl_xor(accB.z, m, 64);
            accB.w += __shfl_xor(accB.w, m, 64);
        }

        if (grp == 0) {
            lds_sred[wave][sub * 4 + 0] = accA.x;
            lds_sred[wave][sub * 4 + 1] = accA.y;
            lds_sred[wave][sub * 4 + 2] = accA.z;
            lds_sred[wave][sub * 4 + 3] = accA.w;
            lds_sred[wave][32 + sub * 4 + 0] = accB.x;
            lds_sred[wave][32 + sub * 4 + 1] = accB.y;
            lds_sred[wave][32 + sub * 4 + 2] = accB.z;
            lds_sred[wave][32 + sub * 4 + 3] = accB.w;
        }
        __syncthreads();
        if (tid < M) {
            const float v = lds_sred[0][tid] + lds_sred[1][tid]
                          + lds_sred[2][tid] + lds_sred[3][tid];
            atomicAdd(&r_out[(size_t)b * M + tid], v);
        }
        __syncthreads();
    }
}

// ---------------------------------------------------------------------------
extern "C" void kernel_launch(void* const* d_in, const int* in_sizes, int n_in,
                              void* d_out, int out_size, void* d_ws, size_t ws_size,
                              hipStream_t stream) {
    const float* memory = (const float*)d_in[0];
    const float* k      = (const float*)d_in[1];
    const float* beta   = (const float*)d_in[2];
    const float* g      = (const float*)d_in[3];
    const float* s      = (const float*)d_in[4];
    const float* gamma  = (const float*)d_in[5];
    const float* w_prev = (const float*)d_in[6];
    const float* e      = (const float*)d_in[7];
    const float* a      = (const float*)d_in[8];

    float* out    = (float*)d_out;
    float* w_out  = out;                                  // [B, N]
    float* r_out  = out + (size_t)B * N;                  // [B, M]
    float* newmem = out + (size_t)B * N + (size_t)B * M;  // [B, N, M]

    // Co-residency-safe grid size for the cooperative launch (cached).
    static int s_grid = 0;
    if (s_grid == 0) {
        int dev = 0;
        hipGetDevice(&dev);
        int cus = 0;
        hipDeviceGetAttribute(&cus, hipDeviceAttributeMultiprocessorCount, dev);
        int maxb = 0;
        hipOccupancyMaxActiveBlocksPerMultiprocessor(
            &maxb, (const void*)fused_kernel, 256, 0);
        long gg = (long)(cus > 0 ? cus : 256) * (maxb > 0 ? maxb : 1);
        if (gg > 2048) gg = 2048;
        if (gg < 1) gg = 1;
        s_grid = (int)gg;
    }

    void* args[12] = {
        (void*)&memory, (void*)&k, (void*)&beta, (void*)&g, (void*)&s,
        (void*)&gamma, (void*)&w_prev, (void*)&e, (void*)&a,
        (void*)&w_out, (void*)&r_out, (void*)&newmem
    };
    hipLaunchCooperativeKernel((const void*)fused_kernel, dim3(s_grid),
                               dim3(256), args, 0, stream);
}

// Round 3
// 634.209 us; speedup vs baseline: 1.0143x; 1.0143x over previous
//
#include <hip/hip_runtime.h>
#include <hip/hip_cooperative_groups.h>
#include <cmath>

namespace cg = cooperative_groups;

// NTM memory op, fused single cooperative kernel with two grid syncs.
// P1 (8192 chunk-units): p = exp(beta*cosine(memory+eps, k+eps)), per-chunk
//     partial sums -> g_part_s.
// P2 (2048 segment-units, 512 rows each): softmax-normalize + interpolate +
//     circular 3-tap shift + pow(gamma); pv staged in w_out; per-segment pow
//     sums -> g_part_t.
// P3 (8192 chunk-units): w = pv*invn finalized inline (coalesced LDS write),
//     new_memory = memory*(1 - w e^T) + w a^T (nontemporal), r = w^T memory
//     (block partials + 64 atomics per chunk).
//
// R2 lesson: P2/P3 previously had 1024 units on a 2048-block grid -- half the
// machine idle through the heaviest phase (occupancy 44%, 17% BW). Now every
// phase has >= 1 unit per block.
//
// Scratch plan: p staged in the not-yet-written newmem region (written P1,
// read P2, overwritten P3 -- phases separated by grid.sync). pv staged in
// w_out (written P2, read+overwritten P3; each row owned by exactly one
// block-iteration). Reduction partials in __device__ globals, every element
// written before read each launch.

namespace {
constexpr int B = 128;
constexpr int N = 8192;
constexpr int M = 64;
constexpr float F_EPS = 1e-16f;
constexpr float F_COS_EPS = 1e-8f;

constexpr int ROWS = 128;                 // rows per P1/P3 chunk
constexpr int NCHUNK = B * (N / ROWS);    // 8192 chunk units
constexpr int SEGROWS = 512;              // rows per P2 segment
constexpr int SEG_PER_B = N / SEGROWS;    // 16
constexpr int NSEG = B * SEG_PER_B;       // 2048 segment units
}

typedef float vfloat4 __attribute__((ext_vector_type(4)));

__device__ float g_part_s[NCHUNK];   // per-chunk softmax partial sums
__device__ float g_part_t[NSEG];     // per-segment pow partial sums

__global__ __launch_bounds__(256, 4) void fused_kernel(
    const float* __restrict__ memory, const float* __restrict__ k,
    const float* __restrict__ beta, const float* __restrict__ g,
    const float* __restrict__ s, const float* __restrict__ gamma,
    const float* __restrict__ w_prev, const float* __restrict__ e,
    const float* __restrict__ a, float* __restrict__ w_out,
    float* __restrict__ r_out, float* __restrict__ newmem)
{
    const int tid  = threadIdx.x;
    const int wave = tid >> 6;
    const int lane = tid & 63;
    const int grp  = lane >> 3;       // row within 8-row pack
    const int sub  = lane & 7;        // float4 slot (0..7), +8 for hi half
    const int G    = gridDim.x;

    float* const p = newmem;          // exp-score staging (dead after P2)

    __shared__ float lds_red[4];
    __shared__ float lds_wg[SEGROWS + 2];
    __shared__ float lds_w[ROWS];
    __shared__ float lds_sred[4][M];

    // ------------------------- Phase 1: scores -------------------------
    for (int u = blockIdx.x; u < NCHUNK; u += G) {
        const int b     = u >> 6;
        const int chunk = u & 63;

        // zero the r accumulator (first 32 units cover B*M floats)
        if (u < (B * M) / 256) r_out[u * 256 + tid] = 0.0f;

        const float4* k4 = reinterpret_cast<const float4*>(k + (size_t)b * M);
        const float4 kva = k4[sub];
        const float4 kvb = k4[sub + 8];
        const float4 kea = make_float4(kva.x + F_EPS, kva.y + F_EPS,
                                       kva.z + F_EPS, kva.w + F_EPS);
        const float4 keb = make_float4(kvb.x + F_EPS, kvb.y + F_EPS,
                                       kvb.z + F_EPS, kvb.w + F_EPS);
        float kn2 = kea.x*kea.x + kea.y*kea.y + kea.z*kea.z + kea.w*kea.w
                  + keb.x*keb.x + keb.y*keb.y + keb.z*keb.z + keb.w*keb.w;
        #pragma unroll
        for (int m = 1; m <= 4; m <<= 1) kn2 += __shfl_xor(kn2, m, 64);
        const float knorm = sqrtf(kn2);
        const float bb = beta[b];

        const int row0 = chunk * ROWS + wave * 32;
        float psum = 0.0f;

        #pragma unroll
        for (int it = 0; it < 4; ++it) {
            const int row = row0 + it * 8 + grp;
            const float4* m4p = reinterpret_cast<const float4*>(
                memory + ((size_t)b * N + row) * M);
            const float4 mva = m4p[sub];
            const float4 mvb = m4p[sub + 8];
            const float4 mea = make_float4(mva.x + F_EPS, mva.y + F_EPS,
                                           mva.z + F_EPS, mva.w + F_EPS);
            const float4 meb = make_float4(mvb.x + F_EPS, mvb.y + F_EPS,
                                           mvb.z + F_EPS, mvb.w + F_EPS);
            float dot = mea.x*kea.x + mea.y*kea.y + mea.z*kea.z + mea.w*kea.w
                      + meb.x*keb.x + meb.y*keb.y + meb.z*keb.z + meb.w*keb.w;
            float n2  = mea.x*mea.x + mea.y*mea.y + mea.z*mea.z + mea.w*mea.w
                      + meb.x*meb.x + meb.y*meb.y + meb.z*meb.z + meb.w*meb.w;
            #pragma unroll
            for (int m = 1; m <= 4; m <<= 1) {
                dot += __shfl_xor(dot, m, 64);
                n2  += __shfl_xor(n2,  m, 64);
            }
            if (sub == 0) {
                const float denom = fmaxf(sqrtf(n2) * knorm, F_COS_EPS);
                const float pe = expf(bb * (dot / denom));
                p[(size_t)b * N + row] = pe;
                psum += pe;
            }
        }

        psum += __shfl_xor(psum, 8, 64);
        psum += __shfl_xor(psum, 16, 64);
        psum += __shfl_xor(psum, 32, 64);
        if (lane == 0) lds_red[wave] = psum;
        __syncthreads();
        if (tid == 0)
            g_part_s[u] = lds_red[0] + lds_red[1] + lds_red[2] + lds_red[3];
        __syncthreads();
    }

    cg::this_grid().sync();

    // ------------------------- Phase 2: weights ------------------------
    for (int u = blockIdx.x; u < NSEG; u += G) {
        const int b  = u >> 4;
        const int n0 = (u & 15) * SEGROWS;

        // per-wave softmax denominator: sum of 64 chunk partials
        float v = g_part_s[b * 64 + lane];
        #pragma unroll
        for (int m = 1; m <= 32; m <<= 1) v += __shfl_xor(v, m, 64);
        const float invS = 1.0f / v;
        const float gb  = g[b];
        const float gS  = gb * invS;
        const float gmb = 1.0f - gb;

        #pragma unroll
        for (int j = 0; j < SEGROWS / 256; j++) {
            const int loc = tid + j * 256;
            const int idx = b * N + n0 + loc;
            lds_wg[loc + 1] = gS * p[idx] + gmb * w_prev[idx];
        }
        if (tid == 0) {
            const int prev = (n0 - 1) & (N - 1);
            const int next = (n0 + SEGROWS) & (N - 1);
            lds_wg[0] = gS * p[b * N + prev] + gmb * w_prev[b * N + prev];
            lds_wg[SEGROWS + 1] =
                gS * p[b * N + next] + gmb * w_prev[b * N + next];
        }
        __syncthreads();

        const float s0 = s[b*3+0], s1 = s[b*3+1], s2 = s[b*3+2];
        const float gm = gamma[b];
        float lsum = 0.0f;
        #pragma unroll
        for (int j = 0; j < SEGROWS / 256; j++) {
            const int loc = tid + j * 256;
            const float sh = lds_wg[loc] * s0 + lds_wg[loc + 1] * s1
                           + lds_wg[loc + 2] * s2;
            const float pv = powf(sh, gm);
            w_out[b * N + n0 + loc] = pv;     // stage pv (finalized in P3)
            lsum += pv;
        }
        #pragma unroll
        for (int m = 1; m <= 32; m <<= 1) lsum += __shfl_xor(lsum, m, 64);
        if (lane == 0) lds_red[wave] = lsum;
        __syncthreads();
        if (tid == 0)
            g_part_t[u] = lds_red[0] + lds_red[1] + lds_red[2] + lds_red[3];
        __syncthreads();
    }

    cg::this_grid().sync();

    // ---------------- Phase 3: finalize w + read + update ----------------
    for (int u = blockIdx.x; u < NCHUNK; u += G) {
        const int b     = u >> 6;
        const int chunk = u & 63;

        // per-wave pow-sum: 16 per-segment partials of this batch
        float t = (lane < SEG_PER_B) ? g_part_t[b * SEG_PER_B + lane] : 0.0f;
        #pragma unroll
        for (int m = 1; m <= 8; m <<= 1) t += __shfl_xor(t, m, 64);
        t = __shfl(t, 0, 64);
        const float invn = 1.0f / (t + F_EPS);

        const float4* e4 = reinterpret_cast<const float4*>(e + (size_t)b * M);
        const float4* a4 = reinterpret_cast<const float4*>(a + (size_t)b * M);
        const float4 eva = e4[sub], evb = e4[sub + 8];
        const float4 ava = a4[sub], avb = a4[sub + 8];

        float4 accA = make_float4(0.f, 0.f, 0.f, 0.f);
        float4 accB = make_float4(0.f, 0.f, 0.f, 0.f);
        const int row0 = chunk * ROWS + wave * 32;

        #pragma unroll
        for (int it = 0; it < 4; ++it) {
            const int row = row0 + it * 8 + grp;
            const size_t off = ((size_t)b * N + row) * M;
            const float4* m4p = reinterpret_cast<const float4*>(memory + off);
            const float4 mva = m4p[sub];
            const float4 mvb = m4p[sub + 8];
            const float ww = w_out[(size_t)b * N + row] * invn;  // finalize
            if (sub == 0) lds_w[row - chunk * ROWS] = ww;

            vfloat4 nva, nvb;
            nva.x = mva.x * (1.0f - ww * eva.x) + ww * ava.x;
            nva.y = mva.y * (1.0f - ww * eva.y) + ww * ava.y;
            nva.z = mva.z * (1.0f - ww * eva.z) + ww * ava.z;
            nva.w = mva.w * (1.0f - ww * eva.w) + ww * ava.w;
            nvb.x = mvb.x * (1.0f - ww * evb.x) + ww * avb.x;
            nvb.y = mvb.y * (1.0f - ww * evb.y) + ww * avb.y;
            nvb.z = mvb.z * (1.0f - ww * evb.z) + ww * avb.z;
            nvb.w = mvb.w * (1.0f - ww * evb.w) + ww * avb.w;
            __builtin_nontemporal_store(nva, (vfloat4*)(newmem + off) + sub);
            __builtin_nontemporal_store(nvb, (vfloat4*)(newmem + off) + sub + 8);

            accA.x += ww * mva.x;  accA.y += ww * mva.y;
            accA.z += ww * mva.z;  accA.w += ww * mva.w;
            accB.x += ww * mvb.x;  accB.y += ww * mvb.y;
            accB.z += ww * mvb.z;  accB.w += ww * mvb.w;
        }

        #pragma unroll
        for (int m = 8; m <= 32; m <<= 1) {
            accA.x += __shfl_xor(accA.x, m, 64);
            accA.y += __shfl_xor(accA.y, m, 64);
            accA.z += __shfl_xor(accA.z, m, 64);
            accA.w += __shfl_xor(accA.w, m, 64);
            accB.x += __shfl_xor(accB.x, m, 64);
            accB.y += __shfl_xor(accB.y, m, 64);
            accB.z += __shfl_xor(accB.z, m, 64);
            accB.w += __shfl_xor(accB.w, m, 64);
        }

        if (grp == 0) {
            lds_sred[wave][sub * 4 + 0] = accA.x;
            lds_sred[wave][sub * 4 + 1] = accA.y;
            lds_sred[wave][sub * 4 + 2] = accA.z;
            lds_sred[wave][sub * 4 + 3] = accA.w;
            lds_sred[wave][32 + sub * 4 + 0] = accB.x;
            lds_sred[wave][32 + sub * 4 + 1] = accB.y;
            lds_sred[wave][32 + sub * 4 + 2] = accB.z;
            lds_sred[wave][32 + sub * 4 + 3] = accB.w;
        }
        __syncthreads();
        // coalesced final-w write (512 B per chunk) + r atomics
        if (tid < ROWS)
            w_out[(size_t)b * N + chunk * ROWS + tid] = lds_w[tid];
        else if (tid >= 128 && tid < 128 + M) {
            const int m = tid - 128;
            const float vv = lds_sred[0][m] + lds_sred[1][m]
                           + lds_sred[2][m] + lds_sred[3][m];
            atomicAdd(&r_out[(size_t)b * M + m], vv);
        }
        __syncthreads();
    }
}

// ---------------------------------------------------------------------------
extern "C" void kernel_launch(void* const* d_in, const int* in_sizes, int n_in,
                              void* d_out, int out_size, void* d_ws, size_t ws_size,
                              hipStream_t stream) {
    const float* memory = (const float*)d_in[0];
    const float* k      = (const float*)d_in[1];
    const float* beta   = (const float*)d_in[2];
    const float* g      = (const float*)d_in[3];
    const float* s      = (const float*)d_in[4];
    const float* gamma  = (const float*)d_in[5];
    const float* w_prev = (const float*)d_in[6];
    const float* e      = (const float*)d_in[7];
    const float* a      = (const float*)d_in[8];

    float* out    = (float*)d_out;
    float* w_out  = out;                                  // [B, N]
    float* r_out  = out + (size_t)B * N;                  // [B, M]
    float* newmem = out + (size_t)B * N + (size_t)B * M;  // [B, N, M]

    // Co-residency-safe grid size for the cooperative launch (cached).
    static int s_grid = 0;
    if (s_grid == 0) {
        int dev = 0;
        hipGetDevice(&dev);
        int cus = 0;
        hipDeviceGetAttribute(&cus, hipDeviceAttributeMultiprocessorCount, dev);
        int maxb = 0;
        hipOccupancyMaxActiveBlocksPerMultiprocessor(
            &maxb, (const void*)fused_kernel, 256, 0);
        long gg = (long)(cus > 0 ? cus : 256) * (maxb > 0 ? maxb : 1);
        if (gg > 2048) gg = 2048;
        if (gg < 1) gg = 1;
        s_grid = (int)gg;
    }

    void* args[12] = {
        (void*)&memory, (void*)&k, (void*)&beta, (void*)&g, (void*)&s,
        (void*)&gamma, (void*)&w_prev, (void*)&e, (void*)&a,
        (void*)&w_out, (void*)&r_out, (void*)&newmem
    };
    hipLaunchCooperativeKernel((const void*)fused_kernel, dim3(s_grid),
                               dim3(256), args, 0, stream);
}

// Round 4
// 510.105 us; speedup vs baseline: 1.2610x; 1.2433x over previous
//
#include <hip/hip_runtime.h>
#include <cmath>

// NTM memory op: address (cosine softmax + interpolate + shift + sharpen),
// read r = w^T memory, write new_memory = memory*(1 - w e^T) + w a^T.
// B=128, N=8192, M=64, fp32. Three kernels, stream-ordered.
//
// R2/R3 lesson: single fused cooperative kernel with grid syncs was 126us
// SLOWER than this 3-kernel structure at identical HBM traffic (grid-barrier
// latency + lockstep phases). Reverted.
//
// Traffic plan: memory (256 MiB) read twice (score, update), second read
// L3-resident (FETCH_SIZE 0.27 GB confirms); newmem written once with
// nontemporal stores. p = exp(beta*cos) staged in the not-yet-written newmem
// region; per-chunk softmax partials staged in the r region, consumed then
// zeroed by weight_kernel before update_kernel's atomics accumulate r.
//
// R4: score restructured to ONE ROW PER THREAD -- 16 independent float4
// loads per thread (16-deep MLP), zero mid-loop cross-lane ops (was 2x
// 3-stage shuffle chains per row), k broadcast from LDS, coalesced p write,
// one block reduction per 256 rows. update deepened to 256 rows/block
// (16 loads in flight per lane, half the r atomics).

namespace {
constexpr int B = 128;
constexpr int N = 8192;
constexpr int M = 64;
constexpr float F_EPS = 1e-16f;
constexpr float F_COS_EPS = 1e-8f;

constexpr int SROWS = 256;             // rows per score block (1 per thread)
constexpr int SCHUNKS = N / SROWS;     // 32 chunks per batch
constexpr int UROWS = 256;             // rows per update block
constexpr int UCHUNKS = N / UROWS;     // 32 chunks per batch
constexpr int T2 = 1024;               // threads for weight kernel
constexpr int PER = N / T2;            // 8 elements per thread
}

typedef float vfloat4 __attribute__((ext_vector_type(4)));

// ---------------------------------------------------------------------------
// Kernel 1: p[b][n] = exp(beta[b] * cosine(memory[b][n]+eps, k[b]+eps)).
// One row per thread: 16 float4 loads in flight, per-thread register
// accumulation, no cross-lane traffic until the per-block psum reduce.
// Writes per-chunk partial sums of p into partial[b*M + chunk] (chunk < 32).
// ---------------------------------------------------------------------------
__global__ __launch_bounds__(256) void score_kernel(
    const float* __restrict__ memory, const float* __restrict__ k,
    const float* __restrict__ beta, float* __restrict__ p_out,
    float* __restrict__ partial)
{
    const int b     = blockIdx.x >> 5;            // / SCHUNKS
    const int chunk = blockIdx.x & (SCHUNKS - 1);
    const int tid   = threadIdx.x;
    const int lane  = tid & 63;
    const int wave  = tid >> 6;

    __shared__ float kl[M];
    __shared__ float red[4];

    if (tid < M) kl[tid] = k[(size_t)b * M + tid] + F_EPS;
    __syncthreads();

    const int row = chunk * SROWS + tid;
    const float4* mrow =
        reinterpret_cast<const float4*>(memory + ((size_t)b * N + row) * M);
    const float4* k4 = reinterpret_cast<const float4*>(kl);

    float dot = 0.f, n2 = 0.f, kn2 = 0.f;
    #pragma unroll
    for (int j = 0; j < M / 4; ++j) {
        const float4 mv = mrow[j];
        const float4 kv = k4[j];
        const float mx = mv.x + F_EPS, my = mv.y + F_EPS,
                    mz = mv.z + F_EPS, mw = mv.w + F_EPS;
        dot += mx*kv.x + my*kv.y + mz*kv.z + mw*kv.w;
        n2  += mx*mx + my*my + mz*mz + mw*mw;
        kn2 += kv.x*kv.x + kv.y*kv.y + kv.z*kv.z + kv.w*kv.w;
    }

    const float denom = fmaxf(sqrtf(n2) * sqrtf(kn2), F_COS_EPS);
    const float pe = expf(beta[b] * (dot / denom));
    p_out[(size_t)b * N + row] = pe;

    float psum = pe;
    #pragma unroll
    for (int m = 1; m <= 32; m <<= 1) psum += __shfl_xor(psum, m, 64);
    if (lane == 0) red[wave] = psum;
    __syncthreads();
    if (tid == 0)
        partial[(size_t)b * M + chunk] = red[0] + red[1] + red[2] + red[3];
}

// ---------------------------------------------------------------------------
// Kernel 2: one block (1024 thr) per batch. Normalize p -> softmax weight,
// interpolate with w_prev, circular 3-tap shift, pow(gamma), renormalize.
// Reads then zeroes the r region (which held the 32 softmax partials).
// ---------------------------------------------------------------------------
__global__ __launch_bounds__(T2) void weight_kernel(
    const float* __restrict__ p, const float* __restrict__ g,
    const float* __restrict__ s, const float* __restrict__ gamma,
    const float* __restrict__ w_prev, float* __restrict__ w_out,
    float* __restrict__ r_out)
{
    const int b    = blockIdx.x;
    const int tid  = threadIdx.x;
    const int lane = tid & 63;
    const int wave = tid >> 6;

    __shared__ float wg[N];          // 32 KB
    __shared__ float red[T2 / 64];   // 16 waves
    __shared__ float sS;

    // Issue the big streaming loads first; latency overlaps the reduce below.
    float pv_r[PER], wp_r[PER];
    #pragma unroll
    for (int i = 0; i < PER; i++) {
        const int idx = tid + i * T2;
        pv_r[i] = p[(size_t)b * N + idx];
        wp_r[i] = w_prev[(size_t)b * N + idx];
    }

    // Sum the 32 per-chunk softmax partials (stored in the r region).
    if (tid < 32) {
        float v = r_out[(size_t)b * M + tid];
        #pragma unroll
        for (int m = 1; m <= 16; m <<= 1) v += __shfl_xor(v, m, 64);
        if (tid == 0) sS = v;
    }
    __syncthreads();
    const float invS = 1.0f / sS;

    // Zero the r accumulator region (consumed by update_kernel's atomics).
    if (tid < M) r_out[(size_t)b * M + tid] = 0.0f;

    const float gb  = g[b];
    const float gS  = gb * invS;
    const float gmb = 1.0f - gb;
    #pragma unroll
    for (int i = 0; i < PER; i++) {
        const int idx = tid + i * T2;
        wg[idx] = gS * pv_r[i] + gmb * wp_r[i];
    }
    __syncthreads();

    const float s0 = s[b * 3 + 0], s1 = s[b * 3 + 1], s2 = s[b * 3 + 2];
    const float gm = gamma[b];
    float pv[PER];
    float lsum = 0.0f;
    #pragma unroll
    for (int i = 0; i < PER; i++) {
        const int idx = tid + i * T2;
        const float sh = wg[(idx - 1) & (N - 1)] * s0
                       + wg[idx] * s1
                       + wg[(idx + 1) & (N - 1)] * s2;
        pv[i] = powf(sh, gm);
        lsum += pv[i];
    }
    #pragma unroll
    for (int m = 1; m <= 32; m <<= 1) lsum += __shfl_xor(lsum, m, 64);
    if (lane == 0) red[wave] = lsum;
    __syncthreads();
    float bsum = 0.0f;
    #pragma unroll
    for (int i = 0; i < T2 / 64; i++) bsum += red[i];
    const float invn = 1.0f / (bsum + F_EPS);

    #pragma unroll
    for (int i = 0; i < PER; i++) {
        const int idx = tid + i * T2;
        w_out[(size_t)b * N + idx] = pv[i] * invn;
    }
}

// ---------------------------------------------------------------------------
// Kernel 3: new_memory = memory*(1 - w e^T) + w a^T (nontemporal stores),
// fused with r[b][m] = sum_n w[b][n]*memory[b][n][m] (block partials +
// one atomicAdd per element per block). 8 lanes per row, 256 rows per block,
// fully unrolled 8-deep (16 loads in flight per lane).
// ---------------------------------------------------------------------------
__global__ __launch_bounds__(256) void update_kernel(
    const float* __restrict__ memory, const float* __restrict__ e,
    const float* __restrict__ a, const float* __restrict__ w,
    float* __restrict__ newmem, float* __restrict__ r_out)
{
    const int b     = blockIdx.x >> 5;            // / UCHUNKS
    const int chunk = blockIdx.x & (UCHUNKS - 1);
    const int wave  = threadIdx.x >> 6;
    const int lane  = threadIdx.x & 63;
    const int grp   = lane >> 3;
    const int sub   = lane & 7;

    const float4* e4 = reinterpret_cast<const float4*>(e + (size_t)b * M);
    const float4* a4 = reinterpret_cast<const float4*>(a + (size_t)b * M);
    const float4 eva = e4[sub], evb = e4[sub + 8];
    const float4 ava = a4[sub], avb = a4[sub + 8];

    const int row0 = chunk * UROWS + wave * (UROWS / 4);   // 64 rows per wave

    float4 accA = make_float4(0.f, 0.f, 0.f, 0.f);
    float4 accB = make_float4(0.f, 0.f, 0.f, 0.f);

    #pragma unroll
    for (int it = 0; it < 8; ++it) {
        const int row = row0 + it * 8 + grp;
        const size_t off = ((size_t)b * N + row) * M;
        const float4* m4p = reinterpret_cast<const float4*>(memory + off);
        const float4 mva = m4p[sub];
        const float4 mvb = m4p[sub + 8];
        const float ww = w[(size_t)b * N + row];

        vfloat4 nva, nvb;
        nva.x = mva.x * (1.0f - ww * eva.x) + ww * ava.x;
        nva.y = mva.y * (1.0f - ww * eva.y) + ww * ava.y;
        nva.z = mva.z * (1.0f - ww * eva.z) + ww * ava.z;
        nva.w = mva.w * (1.0f - ww * eva.w) + ww * ava.w;
        nvb.x = mvb.x * (1.0f - ww * evb.x) + ww * avb.x;
        nvb.y = mvb.y * (1.0f - ww * evb.y) + ww * avb.y;
        nvb.z = mvb.z * (1.0f - ww * evb.z) + ww * avb.z;
        nvb.w = mvb.w * (1.0f - ww * evb.w) + ww * avb.w;
        __builtin_nontemporal_store(nva, (vfloat4*)(newmem + off) + sub);
        __builtin_nontemporal_store(nvb, (vfloat4*)(newmem + off) + sub + 8);

        accA.x += ww * mva.x;  accA.y += ww * mva.y;
        accA.z += ww * mva.z;  accA.w += ww * mva.w;
        accB.x += ww * mvb.x;  accB.y += ww * mvb.y;
        accB.z += ww * mvb.z;  accB.w += ww * mvb.w;
    }

    // Reduce across the 8 row-groups (lanes differing in bits 3,4,5).
    #pragma unroll
    for (int m = 8; m <= 32; m <<= 1) {
        accA.x += __shfl_xor(accA.x, m, 64);
        accA.y += __shfl_xor(accA.y, m, 64);
        accA.z += __shfl_xor(accA.z, m, 64);
        accA.w += __shfl_xor(accA.w, m, 64);
        accB.x += __shfl_xor(accB.x, m, 64);
        accB.y += __shfl_xor(accB.y, m, 64);
        accB.z += __shfl_xor(accB.z, m, 64);
        accB.w += __shfl_xor(accB.w, m, 64);
    }

    __shared__ float sred[4][M];
    if (grp == 0) {
        sred[wave][sub * 4 + 0] = accA.x;
        sred[wave][sub * 4 + 1] = accA.y;
        sred[wave][sub * 4 + 2] = accA.z;
        sred[wave][sub * 4 + 3] = accA.w;
        sred[wave][32 + sub * 4 + 0] = accB.x;
        sred[wave][32 + sub * 4 + 1] = accB.y;
        sred[wave][32 + sub * 4 + 2] = accB.z;
        sred[wave][32 + sub * 4 + 3] = accB.w;
    }
    __syncthreads();
    if (threadIdx.x < M) {
        const float v = sred[0][threadIdx.x] + sred[1][threadIdx.x]
                      + sred[2][threadIdx.x] + sred[3][threadIdx.x];
        atomicAdd(&r_out[(size_t)b * M + threadIdx.x], v);
    }
}

// ---------------------------------------------------------------------------
extern "C" void kernel_launch(void* const* d_in, const int* in_sizes, int n_in,
                              void* d_out, int out_size, void* d_ws, size_t ws_size,
                              hipStream_t stream) {
    const float* memory = (const float*)d_in[0];
    const float* k      = (const float*)d_in[1];
    const float* beta   = (const float*)d_in[2];
    const float* g      = (const float*)d_in[3];
    const float* s      = (const float*)d_in[4];
    const float* gamma  = (const float*)d_in[5];
    const float* w_prev = (const float*)d_in[6];
    const float* e      = (const float*)d_in[7];
    const float* a      = (const float*)d_in[8];

    float* out    = (float*)d_out;
    float* w_out  = out;                                  // [B, N]
    float* r_out  = out + (size_t)B * N;                  // [B, M]
    float* newmem = out + (size_t)B * N + (size_t)B * M;  // [B, N, M]

    // p = exp(scores) staged in the not-yet-written new_memory region;
    // softmax partial sums staged in the r region (32 per batch, stride M).
    float* p       = newmem;
    float* partsum = r_out;

    score_kernel<<<dim3(B * SCHUNKS), dim3(256), 0, stream>>>(
        memory, k, beta, p, partsum);
    weight_kernel<<<dim3(B), dim3(T2), 0, stream>>>(p, g, s, gamma,
                                                    w_prev, w_out, r_out);
    update_kernel<<<dim3(B * UCHUNKS), dim3(256), 0, stream>>>(
        memory, e, a, w_out, newmem, r_out);
}